// Round 1
// baseline (287.723 us; speedup 1.0000x reference)
//
#include <hip/hip_runtime.h>
#include <math.h>

#define BATCH 64
#define NCLS  81
#define NANCH 8732
#define NG    (NANCH / 4)            // 2183 float4 groups per (b, channel-row)
#define BLK   256
#define BPB   ((NG + BLK - 1) / BLK) // 9 blocks per batch

struct Accum {
    float loc[BATCH];    // sum mask * loc
    float posc[BATCH];   // sum mask * closs
    float negc[BATCH];   // sum (1-mask) * closs
    int   cnt[BATCH];    // num_pos
};

__device__ inline float smooth_l1(float d) {
    float a = fabsf(d);
    return (a < 1.f) ? 0.5f * a * a : a - 0.5f;
}

// -------- kernel 0: zero accumulators + output (ws/out are poisoned 0xAA) -----
__global__ void k_init(Accum* __restrict__ acc, float* __restrict__ out) {
    unsigned int* w = (unsigned int*)acc;     // sizeof(Accum) == 256 words
    w[threadIdx.x] = 0u;
    if (threadIdx.x == 0) out[0] = 0.f;
}

// -------- kernel 1: per-column closs + loc, block-reduced into per-batch acc --
__global__ __launch_bounds__(256) void k_main(
    const float* __restrict__ ploc, const float* __restrict__ plabel,
    const float* __restrict__ gloc, const int* __restrict__ glabel,
    const float* __restrict__ dboxes, Accum* __restrict__ acc)
{
    const int b   = blockIdx.x / BPB;
    const int gid = (blockIdx.x % BPB) * BLK + threadIdx.x;

    float l_loc = 0.f, l_posc = 0.f, l_negc = 0.f;
    int   l_cnt = 0;

    if (gid < NG) {
        const float4* pl4 = (const float4*)(plabel + (size_t)b * NCLS * NANCH);
        const int4*   gp  = (const int4*)(glabel + (size_t)b * NANCH);
        const int4    gi  = gp[gid];
        const int g[4] = {gi.x, gi.y, gi.z, gi.w};

        // online logsumexp over NCLS channels, 4 columns at a time
        float m[4], s[4], xg[4];
#pragma unroll
        for (int i = 0; i < 4; ++i) { m[i] = -INFINITY; s[i] = 0.f; xg[i] = 0.f; }

        for (int c = 0; c < NCLS; ++c) {
            float4 xv = pl4[c * NG + gid];
            float x[4] = {xv.x, xv.y, xv.z, xv.w};
#pragma unroll
            for (int i = 0; i < 4; ++i) {
                float nm = fmaxf(m[i], x[i]);
                float e  = __expf(fminf(m[i], x[i]) - nm);   // one exp per element
                s[i] = (x[i] > m[i]) ? s[i] * e + 1.f : s[i] + e;
                m[i] = nm;
                if (c == g[i]) xg[i] = x[i];
            }
        }

        // localization term
        const float4* pploc = (const float4*)(ploc + (size_t)b * 4 * NANCH);
        const float4* pgloc = (const float4*)(gloc + (size_t)b * 4 * NANCH);
        const float4* pdb   = (const float4*)dboxes;
        float P[4][4], G[4][4], D[4][4];   // [channel][column]
#pragma unroll
        for (int ch = 0; ch < 4; ++ch) {
            float4 p = pploc[ch * NG + gid];
            float4 q = pgloc[ch * NG + gid];
            float4 d = pdb[ch * NG + gid];
            P[ch][0]=p.x; P[ch][1]=p.y; P[ch][2]=p.z; P[ch][3]=p.w;
            G[ch][0]=q.x; G[ch][1]=q.y; G[ch][2]=q.z; G[ch][3]=q.w;
            D[ch][0]=d.x; D[ch][1]=d.y; D[ch][2]=d.z; D[ch][3]=d.w;
        }

#pragma unroll
        for (int i = 0; i < 4; ++i) {
            float gx = (G[0][i] - D[0][i]) / D[2][i];
            float gy = (G[1][i] - D[1][i]) / D[3][i];
            float gw = __logf(G[2][i] / D[2][i]);
            float gh = __logf(G[3][i] / D[3][i]);
            float loc_i = smooth_l1(P[0][i] - gx) + smooth_l1(P[1][i] - gy)
                        + smooth_l1(P[2][i] - gw) + smooth_l1(P[3][i] - gh);
            float closs = m[i] + __logf(s[i]) - xg[i];
            bool  mk = g[i] > 0;
            l_loc  += mk ? loc_i : 0.f;
            l_posc += mk ? closs : 0.f;
            l_negc += mk ? 0.f : closs;
            l_cnt  += mk ? 1 : 0;
        }
    }

    // block reduction: 64-lane shuffle, then LDS across 4 waves
#pragma unroll
    for (int off = 32; off; off >>= 1) {
        l_loc  += __shfl_down(l_loc, off);
        l_posc += __shfl_down(l_posc, off);
        l_negc += __shfl_down(l_negc, off);
        l_cnt  += __shfl_down(l_cnt, off);
    }
    __shared__ float sl[4], sp[4], sn[4];
    __shared__ int   sc[4];
    const int wave = threadIdx.x >> 6, lane = threadIdx.x & 63;
    if (lane == 0) { sl[wave] = l_loc; sp[wave] = l_posc; sn[wave] = l_negc; sc[wave] = l_cnt; }
    __syncthreads();
    if (threadIdx.x == 0) {
        float a = 0.f, p = 0.f, n = 0.f; int ct = 0;
#pragma unroll
        for (int w = 0; w < 4; ++w) { a += sl[w]; p += sp[w]; n += sn[w]; ct += sc[w]; }
        atomicAdd(&acc->loc[b],  a);
        atomicAdd(&acc->posc[b], p);
        atomicAdd(&acc->negc[b], n);
        atomicAdd(&acc->cnt[b],  ct);
    }
}

// cold-path helper: recompute closs for one (b, n) column
__device__ float closs_at(const float* __restrict__ plabel, int b, int n, int g) {
    const float* p = plabel + (size_t)b * NCLS * NANCH + n;
    float m = -INFINITY, s = 0.f, xg = 0.f;
    for (int c = 0; c < NCLS; ++c) {
        float x = p[(size_t)c * NANCH];
        float nm = fmaxf(m, x);
        float e  = __expf(fminf(m, x) - nm);
        s = (x > m) ? s * e + 1.f : s + e;
        m = nm;
        if (c == g) xg = x;
    }
    return m + __logf(s) - xg;
}

// -------- kernel 2: per-batch hard-negative selection + final scalar ----------
__global__ __launch_bounds__(256) void k_finalize(
    const float* __restrict__ plabel, const int* __restrict__ glabel,
    Accum* __restrict__ acc, float* __restrict__ out)
{
    const int b = blockIdx.x;
    const int tid = threadIdx.x;
    const int np = acc->cnt[b];
    if (np == 0) return;                      // num_mask == 0 -> contributes 0

    __shared__ float s_sel;
    __shared__ float rs[4], rc[4];
    __shared__ unsigned int hist[256];
    __shared__ unsigned int s_bucket;
    __shared__ long long s_rnext;

    long long K = 3LL * np; if (K > NANCH) K = NANCH;
    const int nn = NANCH - np;

    if ((long long)nn <= K) {
        // all negatives selected; plus first (K - nn) positives by index
        long long extra = K - nn;
        if (extra >= np) {
            if (tid == 0) s_sel = acc->negc[b] + acc->posc[b];
        } else {
            // wave-0 ballot prefix scan over positives in index order (cold path)
            if (tid < 64) {
                long long cnt = 0; float sum = 0.f;
                for (int base = 0; base < NANCH; base += 64) {
                    int n = base + tid;
                    int gl = (n < NANCH) ? glabel[(size_t)b * NANCH + n] : 0;
                    bool p = gl > 0;
                    unsigned long long bal = __ballot(p);
                    int r = __popcll(bal & ((1ull << tid) - 1ull));
                    if (p && (cnt + r) < extra) sum += closs_at(plabel, b, n, gl);
                    cnt += (long long)__popcll(bal);
                }
#pragma unroll
                for (int off = 32; off; off >>= 1) sum += __shfl_down(sum, off);
                if (tid == 0) s_sel = acc->negc[b] + sum;
            }
        }
    } else {
        // cold path: top-K sum of con_neg via 4-level radix-select on float bits
        unsigned int prefix = 0;
        long long r = K;
        for (int level = 3; level >= 0; --level) {
            const int shift = level * 8;
            hist[tid] = 0u;
            __syncthreads();
            const unsigned int pmask =
                (level == 3) ? 0u : (0xFFFFFFFFu << ((level + 1) * 8));
            for (int n = tid; n < NANCH; n += 256) {
                int gl = glabel[(size_t)b * NANCH + n];
                float v = (gl > 0) ? 0.f : fmaxf(closs_at(plabel, b, n, gl), 0.f);
                unsigned int bits = __float_as_uint(v);
                if ((bits & pmask) == (prefix & pmask))
                    atomicAdd(&hist[(bits >> shift) & 255u], 1u);
            }
            __syncthreads();
            if (tid == 0) {
                long long acc_c = 0; int bsel = 0;
                for (int i = 255; i >= 0; --i) {
                    if (acc_c + (long long)hist[i] >= r) { bsel = i; break; }
                    acc_c += hist[i];
                }
                s_bucket = (unsigned int)bsel;
                s_rnext  = r - acc_c;
            }
            __syncthreads();
            prefix |= (s_bucket << shift);
            r = s_rnext;
            __syncthreads();
        }
        const float T = __uint_as_float(prefix);
        float lsum = 0.f, lcnt = 0.f;
        for (int n = tid; n < NANCH; n += 256) {
            int gl = glabel[(size_t)b * NANCH + n];
            float v = (gl > 0) ? 0.f : fmaxf(closs_at(plabel, b, n, gl), 0.f);
            if (v > T) { lsum += v; lcnt += 1.f; }
        }
#pragma unroll
        for (int off = 32; off; off >>= 1) {
            lsum += __shfl_down(lsum, off);
            lcnt += __shfl_down(lcnt, off);
        }
        const int wave = tid >> 6, lane = tid & 63;
        if (lane == 0) { rs[wave] = lsum; rc[wave] = lcnt; }
        __syncthreads();
        if (tid == 0) {
            float gsum = 0.f, gcnt = 0.f;
#pragma unroll
            for (int w = 0; w < 4; ++w) { gsum += rs[w]; gcnt += rc[w]; }
            s_sel = gsum + ((float)K - gcnt) * T;
        }
    }

    __syncthreads();
    if (tid == 0) {
        float total = acc->loc[b] + acc->posc[b] + s_sel;
        float npos  = fmaxf((float)np, 1e-6f);
        atomicAdd(out, (total / npos) * (1.0f / BATCH));
    }
}

extern "C" void kernel_launch(void* const* d_in, const int* in_sizes, int n_in,
                              void* d_out, int out_size, void* d_ws, size_t ws_size,
                              hipStream_t stream) {
    const float* ploc   = (const float*)d_in[0];
    const float* plabel = (const float*)d_in[1];
    const float* gloc   = (const float*)d_in[2];
    const int*   glabel = (const int*)d_in[3];
    const float* dboxes = (const float*)d_in[4];
    float* out = (float*)d_out;
    Accum* acc = (Accum*)d_ws;

    hipLaunchKernelGGL(k_init, dim3(1), dim3(256), 0, stream, acc, out);
    hipLaunchKernelGGL(k_main, dim3(BATCH * BPB), dim3(256), 0, stream,
                       ploc, plabel, gloc, glabel, dboxes, acc);
    hipLaunchKernelGGL(k_finalize, dim3(BATCH), dim3(256), 0, stream,
                       plabel, glabel, acc, out);
}